// Round 20
// baseline (95.401 us; speedup 1.0000x reference)
//
#include <hip/hip_runtime.h>
#include <stdint.h>

#define B_  8
#define C_  512
#define L_  1024
#define NH_ 8
#define HD_ 64

typedef __attribute__((ext_vector_type(8))) short short8;
typedef __attribute__((ext_vector_type(4))) short short4v;
typedef __attribute__((ext_vector_type(4))) float f32x4;
typedef __attribute__((ext_vector_type(2))) unsigned uint2v;

#define MFMA(a,b,c) __builtin_amdgcn_mfma_f32_16x16x32_bf16((a),(b),(c),0,0,0)
#define GLD16(g,l) __builtin_amdgcn_global_load_lds( \
    (const __attribute__((address_space(1))) void*)(g), \
    (__attribute__((address_space(3))) void*)(l), 16, 0, 0)

__device__ __forceinline__ unsigned short f2bf(float f) {
  union { float f; unsigned u; } x; x.f = f;
  unsigned r = x.u + 0x7FFFu + ((x.u >> 16) & 1u);
  return (unsigned short)(r >> 16);
}

// packed f32x2 -> bf16x2 (RNE), gfx950 has no builtin -> inline asm (T12)
__device__ __forceinline__ unsigned cvtpk_bf16(float lo, float hi) {
  unsigned r;
  asm("v_cvt_pk_bf16_f32 %0, %1, %2" : "=v"(r) : "v"(lo), "v"(hi));
  return r;
}

// -------- transpose [B,C,L] f32 -> [B,L,C] bf16  (z=0..15) + weight convert (z=16) ----
__global__ __launch_bounds__(256) void k_transpose(
    const float* __restrict__ q, const float* __restrict__ k,
    unsigned short* __restrict__ qf, unsigned short* __restrict__ kf,
    const float* __restrict__ w0, const float* __restrict__ w1,
    const float* __restrict__ w2, const float* __restrict__ w3,
    unsigned short* __restrict__ wdst) {
  const int z = blockIdx.z;
  if (z == 16) {
    const int gb = blockIdx.y * 32 + blockIdx.x;          // 0..511
    const float* s = (gb < 128) ? w0 : (gb < 256) ? w1 : (gb < 384) ? w2 : w3;
    const int off = (gb & 127) * 2048 + threadIdx.x * 8;
    float4 v0 = *(const float4*)&s[off];
    float4 v1 = *(const float4*)&s[off + 4];
    short8 p;
    p[0] = (short)f2bf(v0.x); p[1] = (short)f2bf(v0.y);
    p[2] = (short)f2bf(v0.z); p[3] = (short)f2bf(v0.w);
    p[4] = (short)f2bf(v1.x); p[5] = (short)f2bf(v1.y);
    p[6] = (short)f2bf(v1.z); p[7] = (short)f2bf(v1.w);
    *(short8*)&wdst[(size_t)(gb >> 7) * 262144 + off] = p;
    return;
  }
  __shared__ float t[32][33];
  const int b = z >> 1;
  const float* src = (z & 1) ? k : q;
  unsigned short* dst = (z & 1) ? kf : qf;
  const int tx = threadIdx.x & 31;
  const int ty = threadIdx.x >> 5;           // 0..7
  const int l0 = blockIdx.x * 32;
  const int c0 = blockIdx.y * 32;
#pragma unroll
  for (int i = 0; i < 4; ++i)
    t[ty + 8*i][tx] = src[((size_t)b * C_ + c0 + ty + 8*i) * L_ + l0 + tx];
  __syncthreads();
#pragma unroll
  for (int i = 0; i < 4; ++i)
    dst[((size_t)b * L_ + l0 + ty + 8*i) * C_ + c0 + tx] = f2bf(t[tx][ty + 8*i]);
}

// ---- GEMM core: C[m,n] = sum_k A[m,k]*W[n,k]  (tile (MREP*32) x 128, BK=32) ----
// TRIPLE-buffered with counted vmcnt (T3/T4): per iter
// vmcnt(stage_sz) -> s_barrier -> sched_barrier -> STAGE(t+2) -> compute(t).
// One stage stays in flight across the barrier (never drain to 0 mid-loop).
// XOR chunk swizzle f(row)=(row>>1)&3 on both sides.
template<int MREP>
__device__ __forceinline__ void gemm_core(
    const unsigned short* __restrict__ A, const unsigned short* __restrict__ W,
    const float* __restrict__ bias, void* __restrict__ outp,
    const float* __restrict__ resQ, const float* __restrict__ resK,
    int mode, float scale, unsigned short* lA, unsigned short* lB,
    int tm, int tn) {
  const int lane = threadIdx.x & 63;
  const int wid  = threadIdx.x >> 6;
  const int wm = wid >> 1, wn = wid & 1;
  const int r16 = lane & 15;
  const int g4  = lane >> 4;

  constexpr int ASLOTS = MREP * 128;   // 16B chunks per A buffer
  constexpr int BSLOTS = 512;

  const int sB0 = wid * 128 + lane;
  const int rB0 = sB0 >> 2;
  const int cB0 = (sB0 & 3) ^ ((rB0 >> 1) & 3);
  const int sA0 = wid * (ASLOTS / 4) + lane;
  const int rA0 = sA0 >> 2;
  const int cA0 = (sA0 & 3) ^ ((rA0 >> 1) & 3);

#define G_STAGE(bb, kt) { \
    if constexpr (MREP == 4) { \
      GLD16(A + (size_t)(tm + rA0) * C_ + (kt) + cA0 * 8, &lA[(bb)*ASLOTS*8 + (wid*128)*8]); \
      GLD16(A + (size_t)(tm + rA0 + 16) * C_ + (kt) + cA0 * 8, &lA[(bb)*ASLOTS*8 + (wid*128+64)*8]); \
    } else { \
      GLD16(A + (size_t)(tm + rA0) * C_ + (kt) + cA0 * 8, &lA[(bb)*ASLOTS*8 + (wid*64)*8]); \
    } \
    GLD16(W + (size_t)(tn + rB0) * C_ + (kt) + cB0 * 8, &lB[(bb)*BSLOTS*8 + (wid*128)*8]); \
    GLD16(W + (size_t)(tn + rB0 + 16) * C_ + (kt) + cB0 * 8, &lB[(bb)*BSLOTS*8 + (wid*128+64)*8]); \
  }

  f32x4 acc[MREP][4];
#pragma unroll
  for (int i = 0; i < MREP; ++i)
#pragma unroll
    for (int j = 0; j < 4; ++j) acc[i][j] = (f32x4){0.f, 0.f, 0.f, 0.f};

  G_STAGE(0, 0);
  G_STAGE(1, 32);

  int cur = 0;
#pragma unroll 1
  for (int t = 0; t < 16; ++t) {
    // wait for stage(t): one stage (4 or 3 loads) may remain in flight
    if (t < 15) {
      if constexpr (MREP == 4) asm volatile("s_waitcnt vmcnt(4)" ::: "memory");
      else                     asm volatile("s_waitcnt vmcnt(3)" ::: "memory");
    } else {
      asm volatile("s_waitcnt vmcnt(0)" ::: "memory");
    }
    __builtin_amdgcn_s_barrier();
    __builtin_amdgcn_sched_barrier(0);
    if (t < 14) {
      int nb = cur + 2; if (nb >= 3) nb -= 3;
      G_STAGE(nb, (t + 2) * 32);
    }

    const unsigned short* cAb = &lA[cur * ASLOTS * 8];
    const unsigned short* cBb = &lB[cur * BSLOTS * 8];
    short8 af[MREP], bw[4];
#pragma unroll
    for (int i = 0; i < MREP; ++i) {
      int row = wm * (MREP * 16) + i * 16 + r16;
      af[i] = *(const short8*)&cAb[(row * 4 + (g4 ^ ((row >> 1) & 3))) * 8];
    }
#pragma unroll
    for (int j = 0; j < 4; ++j) {
      int row = wn * 64 + j * 16 + r16;
      bw[j] = *(const short8*)&cBb[(row * 4 + (g4 ^ ((row >> 1) & 3))) * 8];
    }
    __builtin_amdgcn_s_setprio(1);
#pragma unroll
    for (int i = 0; i < MREP; ++i)
#pragma unroll
      for (int j = 0; j < 4; ++j) acc[i][j] = MFMA(af[i], bw[j], acc[i][j]);
    __builtin_amdgcn_s_setprio(0);

    cur = (cur + 1 == 3) ? 0 : cur + 1;
  }
#undef G_STAGE

  if (mode <= 1) {
    unsigned short* out = (unsigned short*)outp;
#pragma unroll
    for (int i = 0; i < MREP; ++i)
#pragma unroll
      for (int j = 0; j < 4; ++j) {
        int c = tn + wn*64 + j*16 + r16;
        float bia = bias[c];
        int h = c >> 6, d = c & 63;
#pragma unroll
        for (int r = 0; r < 4; ++r) {
          int gm = tm + wm*(MREP*16) + i*16 + g4*4 + r;
          int b = gm >> 10, l = gm & 1023;
          out[(((size_t)b * NH_ + h) * L_ + l) * HD_ + d] = f2bf((acc[i][j][r] + bia) * scale);
        }
      }
  } else if (mode == 2) {
    unsigned short* out = (unsigned short*)outp;
#pragma unroll
    for (int i = 0; i < MREP; ++i)
#pragma unroll
      for (int j = 0; j < 4; ++j) {
        int c = tn + wn*64 + j*16 + r16;
        float bia = bias[c];
        int h = c >> 6, d = c & 63;
        int gm0 = tm + wm*(MREP*16) + i*16 + g4*4;
        int b = gm0 >> 10, l0 = gm0 & 1023;
        short4v pk;
#pragma unroll
        for (int r = 0; r < 4; ++r) pk[r] = (short)f2bf(acc[i][j][r] + bia);
        *(short4v*)&out[(((size_t)b * NH_ + h) * HD_ + d) * L_ + l0] = pk;
      }
  } else {
    float* out = (float*)outp;
#pragma unroll
    for (int i = 0; i < MREP; ++i)
#pragma unroll
      for (int j = 0; j < 4; ++j) {
        int c = tn + wn*64 + j*16 + r16;
        float bia = bias[c];
        int gm0 = tm + wm*(MREP*16) + i*16 + g4*4;
        int b = gm0 >> 10, l0 = gm0 & 1023;
        size_t idx = ((size_t)b * C_ + c) * L_ + l0;
        float4 q4 = *(const float4*)&resQ[idx];
        float4 k4 = *(const float4*)&resK[idx];
        float4 o4;
        o4.x = acc[i][j][0] + bia + q4.x + k4.x;
        o4.y = acc[i][j][1] + bia + q4.y + k4.y;
        o4.z = acc[i][j][2] + bia + q4.z + k4.z;
        o4.w = acc[i][j][3] + bia + q4.w + k4.w;
        *(float4*)&out[idx] = o4;
      }
  }
}

// 1D grid, 768 blocks. XCD-grouped. LDS 48KB (3-buf) -> 3 blocks/CU.
__global__ __launch_bounds__(256) void k_proj(
    const unsigned short* __restrict__ qf, const unsigned short* __restrict__ kf,
    const unsigned short* __restrict__ Wqb, const unsigned short* __restrict__ Wkb,
    const unsigned short* __restrict__ Wvb,
    const float* __restrict__ bq, const float* __restrict__ bk, const float* __restrict__ bv,
    unsigned short* __restrict__ Qw, unsigned short* __restrict__ Kw,
    unsigned short* __restrict__ VTw) {
  __shared__ unsigned short lA[3 * 512 * 8];
  __shared__ unsigned short lB[3 * 512 * 8];
  const int bid = blockIdx.x;
  const int xcd = bid & 7;
  const int i_  = bid >> 3;            // 0..95
  const int ml  = i_ / 12;             // 0..7
  const int rem = i_ - ml * 12;        // 0..11
  const int z   = rem >> 2;            // 0..2
  const int n   = rem & 3;             // 0..3
  const int m   = xcd * 8 + ml;        // 0..63
  const unsigned short* A = (z == 0) ? qf : kf;
  const unsigned short* W = (z == 0) ? Wqb : (z == 1) ? Wkb : Wvb;
  const float* bias = (z == 0) ? bq : (z == 1) ? bk : bv;
  void* out = (z == 0) ? (void*)Qw : (z == 1) ? (void*)Kw : (void*)VTw;
  // Q scale folds head-dim scaling AND log2(e) so attn softmax runs in exp2 domain.
  float scale = (z == 0) ? 0.125f * 1.44269504088896f : 1.0f;
  gemm_core<4>(A, W, bias, out, nullptr, nullptr, z, scale, lA, lB, m * 128, n * 128);
}

// 1D grid, 512 blocks (64x128 tile). LDS 36KB (3-buf) -> 4 blocks/CU.
__global__ __launch_bounds__(256) void k_outproj(
    const unsigned short* __restrict__ O, const unsigned short* __restrict__ Wob,
    const float* __restrict__ bo, float* __restrict__ out,
    const float* __restrict__ query, const float* __restrict__ key) {
  __shared__ unsigned short lA[3 * 256 * 8];
  __shared__ unsigned short lB[3 * 512 * 8];
  const int bid = blockIdx.x;
  const int xcd = bid & 7;
  const int i_  = bid >> 3;             // 0..63
  const int m   = xcd * 16 + (i_ >> 2); // 0..127
  const int n   = i_ & 3;
  gemm_core<2>(O, Wob, bo, out, query, key, 3, 1.0f, lA, lB, m * 64, n * 128);
}

// ---------------- flash attention ----------------
// KVBLK=64, TRIPLE-buffered K/V (48KB -> 3 blocks/CU) with counted vmcnt:
// per iter: vmcnt(4) [one 4-load stage in flight] -> s_barrier ->
// sched_barrier -> STAGE(t+2) -> compute(t). QBLK=32/wave, register-P via
// permuted swapped QK^T, static-max exp2 softmax, l on MFMA pipe.
__global__ __launch_bounds__(256, 3) void k_attn(
    const unsigned short* __restrict__ Q, const unsigned short* __restrict__ K,
    const unsigned short* __restrict__ VT, unsigned short* __restrict__ O) {
  __shared__ unsigned short Kt[3][64 * 64];
  __shared__ unsigned short Vt[3][64 * 64];
  const int lane = threadIdx.x & 63;
  const int wid  = threadIdx.x >> 6;
  const int bid  = blockIdx.x;
  const int xcd  = bid & 7;
  const int i_   = bid >> 3;                   // 0..63
  const int bh   = xcd * 8 + (i_ >> 3);        // 0..63, 8 heads per XCD
  const int qb   = i_ & 7;                     // 0..7
  const int qrow0 = qb * 128 + wid * 32;
  const int r16 = lane & 15;
  const int g4  = lane >> 4;
  const size_t base = (size_t)bh * L_ * HD_;
  const unsigned short* Kg = K + base;
  const unsigned short* Vg = VT + base;        // [64 d][1024 l]

  // staging: tile = 64x64 bf16 = 512 slots of 16B; wave stages 128 slots
  // (2 K + 2 V GLD16 = 4 loads/stage). K swizzle f_K(row)=(row>>1)&7;
  // V swizzle f_V(row)=row&7.
  const int s0 = wid * 128 + lane;
  const int row0 = s0 >> 3;
  const int row1 = (s0 + 64) >> 3;
  const int chK0 = (s0 & 7) ^ ((row0 >> 1) & 7);
  const int chK1 = ((s0 + 64) & 7) ^ ((row1 >> 1) & 7);
  const int chV0 = (s0 & 7) ^ (row0 & 7);
  const int chV1 = ((s0 + 64) & 7) ^ (row1 & 7);

#define STAGE_KV(nxt, kt0) { \
    GLD16(Kg + (size_t)((kt0) + row0) * HD_ + chK0 * 8, &Kt[nxt][(wid*128)*8]); \
    GLD16(Kg + (size_t)((kt0) + row1) * HD_ + chK1 * 8, &Kt[nxt][(wid*128+64)*8]); \
    GLD16(Vg + (size_t)row0 * L_ + (kt0) + chV0 * 8, &Vt[nxt][(wid*128)*8]); \
    GLD16(Vg + (size_t)row1 * L_ + (kt0) + chV1 * 8, &Vt[nxt][(wid*128+64)*8]); \
  }

  short8 qv[2][2];
#pragma unroll
  for (int i = 0; i < 2; ++i)
#pragma unroll
    for (int ks = 0; ks < 2; ++ks)
      qv[i][ks] = *(const short8*)(Q + base + (size_t)(qrow0 + i*16 + r16) * HD_ + ks*32 + g4*8);

  short8 vones;
#pragma unroll
  for (int e = 0; e < 8; ++e) vones[e] = (short)0x3F80;   // bf16 1.0

  f32x4 lacc[2];
  f32x4 oacc[2][4];
#pragma unroll
  for (int i = 0; i < 2; ++i) {
    lacc[i] = (f32x4){0.f, 0.f, 0.f, 0.f};
#pragma unroll
    for (int j = 0; j < 4; ++j) oacc[i][j] = (f32x4){0.f, 0.f, 0.f, 0.f};
  }

  STAGE_KV(0, 0);
  STAGE_KV(1, 64);

  // sK = (rr>>1)&7 is h/c-independent: (4*(r16>>2) + (r16&3)) & 7
  const int sK = (4 * (r16 >> 2) + (r16 & 3)) & 7;
  const int swz = r16 & 7;

  int cur = 0;
#pragma unroll 1
  for (int t = 0; t < 16; ++t) {
    if (t < 15) asm volatile("s_waitcnt vmcnt(4)" ::: "memory");
    else        asm volatile("s_waitcnt vmcnt(0)" ::: "memory");
    __builtin_amdgcn_s_barrier();
    __builtin_amdgcn_sched_barrier(0);
    if (t < 14) {
      int nb = cur + 2; if (nb >= 3) nb -= 3;
      STAGE_KV(nb, (t + 2) * 64);
    }

    const unsigned short* lK = &Kt[cur][0];
    const unsigned short* lV = &Vt[cur][0];

    f32x4 sc[2][4];
#pragma unroll
    for (int i = 0; i < 2; ++i)
#pragma unroll
      for (int cf = 0; cf < 4; ++cf) sc[i][cf] = (f32x4){0.f, 0.f, 0.f, 0.f};

    __builtin_amdgcn_s_setprio(1);
#pragma unroll
    for (int cf = 0; cf < 4; ++cf) {
      const int h = cf >> 1, c = cf & 1;
      // permuted K-row: output slot (h,c,g4,r) holds key h*32 + g4*8 + 2r + c
      const int rr = h*32 + ((r16 >> 2) << 3) + ((r16 & 3) << 1) + c;
      const int rowb = rr * 64;
      short8 kb0 = *(const short8*)&lK[rowb + ((g4) ^ sK) * 8];
      short8 kb1 = *(const short8*)&lK[rowb + ((4 + g4) ^ sK) * 8];
      sc[0][cf] = MFMA(kb0, qv[0][0], sc[0][cf]);   // swapped: S^T[k, q]
      sc[0][cf] = MFMA(kb1, qv[0][1], sc[0][cf]);
      sc[1][cf] = MFMA(kb0, qv[1][0], sc[1][cf]);
      sc[1][cf] = MFMA(kb1, qv[1][1], sc[1][cf]);
    }
    __builtin_amdgcn_s_setprio(0);

    // p = exp2(s) (static max: |s|<=~18 << 127); pack PV A-frag in registers.
#pragma unroll
    for (int h = 0; h < 2; ++h) {
      union { unsigned u[4]; short8 s8; } pu0, pu1;
#pragma unroll
      for (int r = 0; r < 4; ++r) {
        pu0.u[r] = cvtpk_bf16(exp2f(sc[0][h*2][r]), exp2f(sc[0][h*2+1][r]));
        pu1.u[r] = cvtpk_bf16(exp2f(sc[1][h*2][r]), exp2f(sc[1][h*2+1][r]));
      }
      short8 pa0 = pu0.s8;
      short8 pa1 = pu1.s8;
      __builtin_amdgcn_s_setprio(1);
      lacc[0] = MFMA(pa0, vones, lacc[0]);
      lacc[1] = MFMA(pa1, vones, lacc[1]);
#pragma unroll
      for (int j = 0; j < 4; ++j) {
        short8 vb = *(const short8*)&lV[(j*16 + r16) * 64 + ((h*4 + g4) ^ swz) * 8];
        oacc[0][j] = MFMA(pa0, vb, oacc[0][j]);
        oacc[1][j] = MFMA(pa1, vb, oacc[1][j]);
      }
      __builtin_amdgcn_s_setprio(0);
    }

    cur = (cur + 1 == 3) ? 0 : cur + 1;
  }
#undef STAGE_KV

  const int b = bh >> 3, h = bh & 7;
#pragma unroll
  for (int i = 0; i < 2; ++i) {
    float linv[4];
#pragma unroll
    for (int r = 0; r < 4; ++r) linv[r] = 1.0f / lacc[i][r];
#pragma unroll
    for (int j = 0; j < 4; ++j)
#pragma unroll
      for (int r = 0; r < 4; ++r) {
        int row = qrow0 + i*16 + g4*4 + r;
        int col = h*64 + j*16 + r16;
        O[((size_t)b * L_ + row) * C_ + col] = f2bf(oacc[i][j][r] * linv[r]);
      }
  }
}

extern "C" void kernel_launch(void* const* d_in, const int* in_sizes, int n_in,
                              void* d_out, int out_size, void* d_ws, size_t ws_size,
                              hipStream_t stream) {
  (void)in_sizes; (void)n_in; (void)out_size; (void)ws_size;
  const float* query = (const float*)d_in[0];
  const float* key   = (const float*)d_in[1];
  const float* Wq = (const float*)d_in[2];
  const float* bq = (const float*)d_in[3];
  const float* Wk = (const float*)d_in[4];
  const float* bk = (const float*)d_in[5];
  const float* Wv = (const float*)d_in[6];
  const float* bv = (const float*)d_in[7];
  const float* Wo = (const float*)d_in[8];
  const float* bo = (const float*)d_in[9];

  char* ws = (char*)d_ws;
  unsigned short* qf  = (unsigned short*)(ws);                  // 8 MB
  unsigned short* kf  = (unsigned short*)(ws + 8388608);        // 8 MB
  unsigned short* Wqb = (unsigned short*)(ws + 16777216);       // 4x 512KB
  unsigned short* Wkb = Wqb + 262144;
  unsigned short* Wvb = Wkb + 262144;
  unsigned short* Wob = Wvb + 262144;
  unsigned short* Qw  = (unsigned short*)(ws + 18874368);       // 8 MB
  unsigned short* Kw  = (unsigned short*)(ws + 27262976);       // 8 MB
  unsigned short* VTw = (unsigned short*)(ws + 35651584);       // 8 MB
  unsigned short* Ow  = (unsigned short*)(ws + 44040192);       // 8 MB

  k_transpose<<<dim3(32, 16, 17), 256, 0, stream>>>(query, key, qf, kf,
                                                    Wq, Wk, Wv, Wo, Wqb);
  k_proj<<<dim3(768), 256, 0, stream>>>(qf, kf, Wqb, Wkb, Wvb, bq, bk, bv, Qw, Kw, VTw);
  k_attn<<<dim3(512), 256, 0, stream>>>(Qw, Kw, VTw, Ow);
  k_outproj<<<dim3(512), 256, 0, stream>>>(Ow, Wob, bo, (float*)d_out, query, key);
}

// Round 21
// 92.095 us; speedup vs baseline: 1.0359x; 1.0359x over previous
//
#include <hip/hip_runtime.h>
#include <stdint.h>

#define B_  8
#define C_  512
#define L_  1024
#define NH_ 8
#define HD_ 64

typedef __attribute__((ext_vector_type(8))) short short8;
typedef __attribute__((ext_vector_type(4))) short short4v;
typedef __attribute__((ext_vector_type(4))) float f32x4;
typedef __attribute__((ext_vector_type(2))) unsigned uint2v;

#define MFMA(a,b,c) __builtin_amdgcn_mfma_f32_16x16x32_bf16((a),(b),(c),0,0,0)
#define GLD16(g,l) __builtin_amdgcn_global_load_lds( \
    (const __attribute__((address_space(1))) void*)(g), \
    (__attribute__((address_space(3))) void*)(l), 16, 0, 0)

__device__ __forceinline__ unsigned short f2bf(float f) {
  union { float f; unsigned u; } x; x.f = f;
  unsigned r = x.u + 0x7FFFu + ((x.u >> 16) & 1u);
  return (unsigned short)(r >> 16);
}

// packed f32x2 -> bf16x2 (RNE), gfx950 has no builtin -> inline asm (T12)
__device__ __forceinline__ unsigned cvtpk_bf16(float lo, float hi) {
  unsigned r;
  asm("v_cvt_pk_bf16_f32 %0, %1, %2" : "=v"(r) : "v"(lo), "v"(hi));
  return r;
}

// -------- transpose [B,C,L] f32 -> [B,L,C] bf16  (z=0..15) + weight convert (z=16) ----
// Store phase packs 2 adjacent channels -> 4B stores (G13: no scalar bf16 stores).
__global__ __launch_bounds__(256) void k_transpose(
    const float* __restrict__ q, const float* __restrict__ k,
    unsigned short* __restrict__ qf, unsigned short* __restrict__ kf,
    const float* __restrict__ w0, const float* __restrict__ w1,
    const float* __restrict__ w2, const float* __restrict__ w3,
    unsigned short* __restrict__ wdst) {
  const int z = blockIdx.z;
  if (z == 16) {
    const int gb = blockIdx.y * 32 + blockIdx.x;          // 0..511
    const float* s = (gb < 128) ? w0 : (gb < 256) ? w1 : (gb < 384) ? w2 : w3;
    const int off = (gb & 127) * 2048 + threadIdx.x * 8;
    float4 v0 = *(const float4*)&s[off];
    float4 v1 = *(const float4*)&s[off + 4];
    short8 p;
    p[0] = (short)f2bf(v0.x); p[1] = (short)f2bf(v0.y);
    p[2] = (short)f2bf(v0.z); p[3] = (short)f2bf(v0.w);
    p[4] = (short)f2bf(v1.x); p[5] = (short)f2bf(v1.y);
    p[6] = (short)f2bf(v1.z); p[7] = (short)f2bf(v1.w);
    *(short8*)&wdst[(size_t)(gb >> 7) * 262144 + off] = p;
    return;
  }
  __shared__ float t[32][33];
  const int b = z >> 1;
  const float* src = (z & 1) ? k : q;
  unsigned short* dst = (z & 1) ? kf : qf;
  const int tx = threadIdx.x & 31;
  const int ty = threadIdx.x >> 5;           // 0..7
  const int l0 = blockIdx.x * 32;
  const int c0 = blockIdx.y * 32;
#pragma unroll
  for (int i = 0; i < 4; ++i)
    t[ty + 8*i][tx] = src[((size_t)b * C_ + c0 + ty + 8*i) * L_ + l0 + tx];
  __syncthreads();
  const int cx = (threadIdx.x & 15) * 2;     // channel pair
  const int ly = threadIdx.x >> 4;           // 0..15
#pragma unroll
  for (int i = 0; i < 2; ++i) {
    const int ll = ly + 16 * i;
    unsigned pk = cvtpk_bf16(t[cx][ll], t[cx + 1][ll]);
    *(unsigned*)&dst[((size_t)b * L_ + l0 + ll) * C_ + c0 + cx] = pk;
  }
}

// ---- GEMM core: C[m,n] = sum_k A[m,k]*W[n,k]  (tile (MREP*32) x 128, BK=32) ----
// Double-buffered 2-phase, XOR chunk swizzle f(row)=(row>>1)&3.
template<int MREP>
__device__ __forceinline__ void gemm_core(
    const unsigned short* __restrict__ A, const unsigned short* __restrict__ W,
    const float* __restrict__ bias, void* __restrict__ outp,
    const float* __restrict__ resQ, const float* __restrict__ resK,
    int mode, float scale, unsigned short* lA, unsigned short* lB,
    int tm, int tn) {
  const int lane = threadIdx.x & 63;
  const int wid  = threadIdx.x >> 6;
  const int wm = wid >> 1, wn = wid & 1;
  const int r16 = lane & 15;
  const int g4  = lane >> 4;

  constexpr int ASLOTS = MREP * 128;   // 16B chunks per A buffer
  constexpr int BSLOTS = 512;

  const int sB0 = wid * 128 + lane;
  const int rB0 = sB0 >> 2;
  const int cB0 = (sB0 & 3) ^ ((rB0 >> 1) & 3);
  const int sA0 = wid * (ASLOTS / 4) + lane;
  const int rA0 = sA0 >> 2;
  const int cA0 = (sA0 & 3) ^ ((rA0 >> 1) & 3);

#define G_STAGE(bb, kt) { \
    if constexpr (MREP == 4) { \
      GLD16(A + (size_t)(tm + rA0) * C_ + (kt) + cA0 * 8, &lA[(bb)*ASLOTS*8 + (wid*128)*8]); \
      GLD16(A + (size_t)(tm + rA0 + 16) * C_ + (kt) + cA0 * 8, &lA[(bb)*ASLOTS*8 + (wid*128+64)*8]); \
    } else { \
      GLD16(A + (size_t)(tm + rA0) * C_ + (kt) + cA0 * 8, &lA[(bb)*ASLOTS*8 + (wid*64)*8]); \
    } \
    GLD16(W + (size_t)(tn + rB0) * C_ + (kt) + cB0 * 8, &lB[(bb)*BSLOTS*8 + (wid*128)*8]); \
    GLD16(W + (size_t)(tn + rB0 + 16) * C_ + (kt) + cB0 * 8, &lB[(bb)*BSLOTS*8 + (wid*128+64)*8]); \
  }

  f32x4 acc[MREP][4];
#pragma unroll
  for (int i = 0; i < MREP; ++i)
#pragma unroll
    for (int j = 0; j < 4; ++j) acc[i][j] = (f32x4){0.f, 0.f, 0.f, 0.f};

  G_STAGE(0, 0);
  __syncthreads();

  int cur = 0;
  for (int t = 0; t < 16; ++t) {
    if (t < 15) G_STAGE(cur ^ 1, (t + 1) * 32);

    const unsigned short* cAb = &lA[cur * ASLOTS * 8];
    const unsigned short* cBb = &lB[cur * BSLOTS * 8];
    short8 af[MREP], bw[4];
#pragma unroll
    for (int i = 0; i < MREP; ++i) {
      int row = wm * (MREP * 16) + i * 16 + r16;
      af[i] = *(const short8*)&cAb[(row * 4 + (g4 ^ ((row >> 1) & 3))) * 8];
    }
#pragma unroll
    for (int j = 0; j < 4; ++j) {
      int row = wn * 64 + j * 16 + r16;
      bw[j] = *(const short8*)&cBb[(row * 4 + (g4 ^ ((row >> 1) & 3))) * 8];
    }
    __builtin_amdgcn_s_setprio(1);
#pragma unroll
    for (int i = 0; i < MREP; ++i)
#pragma unroll
      for (int j = 0; j < 4; ++j) acc[i][j] = MFMA(af[i], bw[j], acc[i][j]);
    __builtin_amdgcn_s_setprio(0);

    __syncthreads();
    cur ^= 1;
  }
#undef G_STAGE

  if (mode <= 1) {
    unsigned short* out = (unsigned short*)outp;
#pragma unroll
    for (int i = 0; i < MREP; ++i)
#pragma unroll
      for (int j = 0; j < 4; ++j) {
        int c = tn + wn*64 + j*16 + r16;
        float bia = bias[c];
        int h = c >> 6, d = c & 63;
#pragma unroll
        for (int r = 0; r < 4; ++r) {
          int gm = tm + wm*(MREP*16) + i*16 + g4*4 + r;
          int b = gm >> 10, l = gm & 1023;
          out[(((size_t)b * NH_ + h) * L_ + l) * HD_ + d] = f2bf((acc[i][j][r] + bia) * scale);
        }
      }
  } else if (mode == 2) {
    unsigned short* out = (unsigned short*)outp;
#pragma unroll
    for (int i = 0; i < MREP; ++i)
#pragma unroll
      for (int j = 0; j < 4; ++j) {
        int c = tn + wn*64 + j*16 + r16;
        float bia = bias[c];
        int h = c >> 6, d = c & 63;
        int gm0 = tm + wm*(MREP*16) + i*16 + g4*4;
        int b = gm0 >> 10, l0 = gm0 & 1023;
        short4v pk;
#pragma unroll
        for (int r = 0; r < 4; ++r) pk[r] = (short)f2bf(acc[i][j][r] + bia);
        *(short4v*)&out[(((size_t)b * NH_ + h) * HD_ + d) * L_ + l0] = pk;
      }
  } else {
    float* out = (float*)outp;
#pragma unroll
    for (int i = 0; i < MREP; ++i)
#pragma unroll
      for (int j = 0; j < 4; ++j) {
        int c = tn + wn*64 + j*16 + r16;
        float bia = bias[c];
        int gm0 = tm + wm*(MREP*16) + i*16 + g4*4;
        int b = gm0 >> 10, l0 = gm0 & 1023;
        size_t idx = ((size_t)b * C_ + c) * L_ + l0;
        float4 q4 = *(const float4*)&resQ[idx];
        float4 k4 = *(const float4*)&resK[idx];
        float4 o4;
        o4.x = acc[i][j][0] + bia + q4.x + k4.x;
        o4.y = acc[i][j][1] + bia + q4.y + k4.y;
        o4.z = acc[i][j][2] + bia + q4.z + k4.z;
        o4.w = acc[i][j][3] + bia + q4.w + k4.w;
        *(float4*)&out[idx] = o4;
      }
  }
}

// 1D grid, 768 blocks. XCD-grouped.
__global__ __launch_bounds__(256) void k_proj(
    const unsigned short* __restrict__ qf, const unsigned short* __restrict__ kf,
    const unsigned short* __restrict__ Wqb, const unsigned short* __restrict__ Wkb,
    const unsigned short* __restrict__ Wvb,
    const float* __restrict__ bq, const float* __restrict__ bk, const float* __restrict__ bv,
    unsigned short* __restrict__ Qw, unsigned short* __restrict__ Kw,
    unsigned short* __restrict__ VTw) {
  __shared__ unsigned short lA[2 * 512 * 8];
  __shared__ unsigned short lB[2 * 512 * 8];
  const int bid = blockIdx.x;
  const int xcd = bid & 7;
  const int i_  = bid >> 3;            // 0..95
  const int ml  = i_ / 12;             // 0..7
  const int rem = i_ - ml * 12;        // 0..11
  const int z   = rem >> 2;            // 0..2
  const int n   = rem & 3;             // 0..3
  const int m   = xcd * 8 + ml;        // 0..63
  const unsigned short* A = (z == 0) ? qf : kf;
  const unsigned short* W = (z == 0) ? Wqb : (z == 1) ? Wkb : Wvb;
  const float* bias = (z == 0) ? bq : (z == 1) ? bk : bv;
  void* out = (z == 0) ? (void*)Qw : (z == 1) ? (void*)Kw : (void*)VTw;
  // Q scale folds head-dim scaling AND log2(e) so attn softmax runs in exp2 domain.
  float scale = (z == 0) ? 0.125f * 1.44269504088896f : 1.0f;
  gemm_core<4>(A, W, bias, out, nullptr, nullptr, z, scale, lA, lB, m * 128, n * 128);
}

// 1D grid, 512 blocks (64x128 tile).
__global__ __launch_bounds__(256) void k_outproj(
    const unsigned short* __restrict__ O, const unsigned short* __restrict__ Wob,
    const float* __restrict__ bo, float* __restrict__ out,
    const float* __restrict__ query, const float* __restrict__ key) {
  __shared__ unsigned short lA[2 * 256 * 8];
  __shared__ unsigned short lB[2 * 512 * 8];
  const int bid = blockIdx.x;
  const int xcd = bid & 7;
  const int i_  = bid >> 3;             // 0..63
  const int m   = xcd * 16 + (i_ >> 2); // 0..127
  const int n   = i_ & 3;
  gemm_core<2>(O, Wob, bo, out, query, key, 3, 1.0f, lA, lB, m * 64, n * 128);
}

// ---------------- flash attention ----------------
// r19 champion: QBLK=32/wave, register-P via permuted swapped QK^T,
// static-max exp2 softmax, l on MFMA pipe, KVBLK=128 double-buffered
// (halves the per-iteration barrier + vmcnt(0) drains vs KVBLK=64).
// K tile [128][64], f_K(row)=(row>>1)&7. V tile [64][128], ch ^ (row&7).
__global__ __launch_bounds__(256, 2) void k_attn(
    const unsigned short* __restrict__ Q, const unsigned short* __restrict__ K,
    const unsigned short* __restrict__ VT, unsigned short* __restrict__ O) {
  __shared__ unsigned short Kt[2][128 * 64];
  __shared__ unsigned short Vt[2][64 * 128];
  const int lane = threadIdx.x & 63;
  const int wid  = threadIdx.x >> 6;
  const int bid  = blockIdx.x;
  const int xcd  = bid & 7;
  const int i_   = bid >> 3;                   // 0..63
  const int bh   = xcd * 8 + (i_ >> 3);        // 0..63, 8 heads per XCD
  const int qb   = i_ & 7;                     // 0..7
  const int qrow0 = qb * 128 + wid * 32;
  const int r16 = lane & 15;
  const int g4  = lane >> 4;
  const size_t base = (size_t)bh * L_ * HD_;
  const unsigned short* Kg = K + base;
  const unsigned short* Vg = VT + base;        // [64 d][1024 l]

  // staging: K tile = 1024 slots of 16B, V tile = 1024 slots; wave stages 256
  // of each via 4 GLD16. K slot s: row=s>>3 (0..127), ch=(s&7)^((row>>1)&7).
  // V slot s: row=s>>4 (0..63), ch=(s&15)^(row&7).
  int rowK[4], chKx[4], rowV[4], chVx[4];
#pragma unroll
  for (int i = 0; i < 4; ++i) {
    const int s = wid * 256 + i * 64 + lane;
    rowK[i] = s >> 3; chKx[i] = (s & 7) ^ ((rowK[i] >> 1) & 7);
    rowV[i] = s >> 4; chVx[i] = (s & 15) ^ (rowV[i] & 7);
  }

#define STAGE_KV(nxt, kt0) { \
    GLD16(Kg + (size_t)((kt0) + rowK[0]) * HD_ + chKx[0] * 8, &Kt[nxt][(wid*256      )*8]); \
    GLD16(Kg + (size_t)((kt0) + rowK[1]) * HD_ + chKx[1] * 8, &Kt[nxt][(wid*256 +  64)*8]); \
    GLD16(Kg + (size_t)((kt0) + rowK[2]) * HD_ + chKx[2] * 8, &Kt[nxt][(wid*256 + 128)*8]); \
    GLD16(Kg + (size_t)((kt0) + rowK[3]) * HD_ + chKx[3] * 8, &Kt[nxt][(wid*256 + 192)*8]); \
    GLD16(Vg + (size_t)rowV[0] * L_ + (kt0) + chVx[0] * 8, &Vt[nxt][(wid*256      )*8]); \
    GLD16(Vg + (size_t)rowV[1] * L_ + (kt0) + chVx[1] * 8, &Vt[nxt][(wid*256 +  64)*8]); \
    GLD16(Vg + (size_t)rowV[2] * L_ + (kt0) + chVx[2] * 8, &Vt[nxt][(wid*256 + 128)*8]); \
    GLD16(Vg + (size_t)rowV[3] * L_ + (kt0) + chVx[3] * 8, &Vt[nxt][(wid*256 + 192)*8]); \
  }

  short8 qv[2][2];
#pragma unroll
  for (int i = 0; i < 2; ++i)
#pragma unroll
    for (int ks = 0; ks < 2; ++ks)
      qv[i][ks] = *(const short8*)(Q + base + (size_t)(qrow0 + i*16 + r16) * HD_ + ks*32 + g4*8);

  short8 vones;
#pragma unroll
  for (int e = 0; e < 8; ++e) vones[e] = (short)0x3F80;   // bf16 1.0

  f32x4 lacc[2];
  f32x4 oacc[2][4];
#pragma unroll
  for (int i = 0; i < 2; ++i) {
    lacc[i] = (f32x4){0.f, 0.f, 0.f, 0.f};
#pragma unroll
    for (int j = 0; j < 4; ++j) oacc[i][j] = (f32x4){0.f, 0.f, 0.f, 0.f};
  }

  STAGE_KV(0, 0);
  __syncthreads();

  // sK = (rr>>1)&7, rr = h*32 + (r16>>2)*8 + (r16&3)*2 + c  -> h-independent
  const int sK = (4 * (r16 >> 2) + (r16 & 3)) & 7;
  const int swz = r16 & 7;

  int cur = 0;
  for (int t = 0; t < 8; ++t) {
    if (t < 7) STAGE_KV(cur ^ 1, (t + 1) * 128);

    const unsigned short* lK = &Kt[cur][0];
    const unsigned short* lV = &Vt[cur][0];

    f32x4 sc[2][8];
#pragma unroll
    for (int i = 0; i < 2; ++i)
#pragma unroll
      for (int cf = 0; cf < 8; ++cf) sc[i][cf] = (f32x4){0.f, 0.f, 0.f, 0.f};

    __builtin_amdgcn_s_setprio(1);
#pragma unroll
    for (int cf = 0; cf < 8; ++cf) {
      const int h = cf >> 1, c = cf & 1;
      // permuted K-row: output slot (h,c,g4,r) holds key h*32 + g4*8 + 2r + c
      const int rr = h*32 + ((r16 >> 2) << 3) + ((r16 & 3) << 1) + c;
      const int rowb = rr * 64;
      short8 kb0 = *(const short8*)&lK[rowb + ((g4) ^ sK) * 8];
      short8 kb1 = *(const short8*)&lK[rowb + ((4 + g4) ^ sK) * 8];
      sc[0][cf] = MFMA(kb0, qv[0][0], sc[0][cf]);   // swapped: S^T[k, q]
      sc[0][cf] = MFMA(kb1, qv[0][1], sc[0][cf]);
      sc[1][cf] = MFMA(kb0, qv[1][0], sc[1][cf]);
      sc[1][cf] = MFMA(kb1, qv[1][1], sc[1][cf]);
    }
    __builtin_amdgcn_s_setprio(0);

    // p = exp2(s) (static max: |s|<=~18 << 127); pack PV A-frag in registers.
#pragma unroll
    for (int h = 0; h < 4; ++h) {
      union { unsigned u[4]; short8 s8; } pu0, pu1;
#pragma unroll
      for (int r = 0; r < 4; ++r) {
        pu0.u[r] = cvtpk_bf16(exp2f(sc[0][h*2][r]), exp2f(sc[0][h*2+1][r]));
        pu1.u[r] = cvtpk_bf16(exp2f(sc[1][h*2][r]), exp2f(sc[1][h*2+1][r]));
      }
      short8 pa0 = pu0.s8;
      short8 pa1 = pu1.s8;
      __builtin_amdgcn_s_setprio(1);
      lacc[0] = MFMA(pa0, vones, lacc[0]);
      lacc[1] = MFMA(pa1, vones, lacc[1]);
#pragma unroll
      for (int j = 0; j < 4; ++j) {
        short8 vb = *(const short8*)&lV[(j*16 + r16) * 128 + ((h*4 + g4) ^ swz) * 8];
        oacc[0][j] = MFMA(pa0, vb, oacc[0][j]);
        oacc[1][j] = MFMA(pa1, vb, oacc[1][j]);
      }
      __builtin_amdgcn_s_setprio(0);
    }

    __syncthreads();
    cur ^= 1;
  }
#undef STAGE_KV

  const int b = bh >> 3, h = bh & 7;
#pragma unroll
  for (int i = 0; i < 2; ++i) {
    float linv[4];
#pragma unroll
    for (int r = 0; r < 4; ++r) linv[r] = 1.0f / lacc[i][r];
#pragma unroll
    for (int j = 0; j < 4; ++j)
#pragma unroll
      for (int r = 0; r < 4; ++r) {
        int row = qrow0 + i*16 + g4*4 + r;
        int col = h*64 + j*16 + r16;
        O[((size_t)b * L_ + row) * C_ + col] = f2bf(oacc[i][j][r] * linv[r]);
      }
  }
}

extern "C" void kernel_launch(void* const* d_in, const int* in_sizes, int n_in,
                              void* d_out, int out_size, void* d_ws, size_t ws_size,
                              hipStream_t stream) {
  (void)in_sizes; (void)n_in; (void)out_size; (void)ws_size;
  const float* query = (const float*)d_in[0];
  const float* key   = (const float*)d_in[1];
  const float* Wq = (const float*)d_in[2];
  const float* bq = (const float*)d_in[3];
  const float* Wk = (const float*)d_in[4];
  const float* bk = (const float*)d_in[5];
  const float* Wv = (const float*)d_in[6];
  const float* bv = (const float*)d_in[7];
  const float* Wo = (const float*)d_in[8];
  const float* bo = (const float*)d_in[9];

  char* ws = (char*)d_ws;
  unsigned short* qf  = (unsigned short*)(ws);                  // 8 MB
  unsigned short* kf  = (unsigned short*)(ws + 8388608);        // 8 MB
  unsigned short* Wqb = (unsigned short*)(ws + 16777216);       // 4x 512KB
  unsigned short* Wkb = Wqb + 262144;
  unsigned short* Wvb = Wkb + 262144;
  unsigned short* Wob = Wvb + 262144;
  unsigned short* Qw  = (unsigned short*)(ws + 18874368);       // 8 MB
  unsigned short* Kw  = (unsigned short*)(ws + 27262976);       // 8 MB
  unsigned short* VTw = (unsigned short*)(ws + 35651584);       // 8 MB
  unsigned short* Ow  = (unsigned short*)(ws + 44040192);       // 8 MB

  k_transpose<<<dim3(32, 16, 17), 256, 0, stream>>>(query, key, qf, kf,
                                                    Wq, Wk, Wv, Wo, Wqb);
  k_proj<<<dim3(768), 256, 0, stream>>>(qf, kf, Wqb, Wkb, Wvb, bq, bk, bv, Qw, Kw, VTw);
  k_attn<<<dim3(512), 256, 0, stream>>>(Qw, Kw, VTw, Ow);
  k_outproj<<<dim3(512), 256, 0, stream>>>(Ow, Wob, bo, (float*)d_out, query, key);
}